// Round 8
// baseline (249.687 us; speedup 1.0000x reference)
//
#include <hip/hip_runtime.h>
#include <cmath>

#define N_   8
#define C_   64
#define H_   160
#define W_   160
#define HW_  25600
#define HH_  80
#define WH_  80
#define FSZ_ (N_ * C_ * HW_)   // 13,107,200
#define PSZ_ (N_ * HW_)        // 204,800

typedef unsigned short ushort8v __attribute__((ext_vector_type(8)));
typedef short          bf16x8  __attribute__((ext_vector_type(8)));
typedef float          f32x4   __attribute__((ext_vector_type(4)));

__device__ __forceinline__ float bf2f(unsigned short u) {
    return __uint_as_float(((unsigned)u) << 16);
}
__device__ __forceinline__ unsigned short f2bf(float f) {
    unsigned u = __float_as_uint(f);
    u += 0x7FFF + ((u >> 16) & 1);          // RNE
    return (unsigned short)(u >> 16);
}

// grid-sample setup: 4 tap indices + weights (align_corners=False, zeros pad)
__device__ __forceinline__ void gs_setup(float bgx, float bgy, float dx, float dy,
                                         int* idx, float* wgt)
{
    float px = ((bgx + dx * (1.f / 160.f)) + 1.f) * 80.f - 0.5f;
    float py = ((bgy + dy * (1.f / 160.f)) + 1.f) * 80.f - 0.5f;
    float x0f = floorf(px), y0f = floorf(py);
    float wx1 = px - x0f, wy1 = py - y0f, wx0 = 1.f - wx1, wy0 = 1.f - wy1;
    int x0 = (int)x0f, y0 = (int)y0f;
    float mx0 = ((unsigned)x0       < (unsigned)W_) ? 1.f : 0.f;
    float mx1 = ((unsigned)(x0 + 1) < (unsigned)W_) ? 1.f : 0.f;
    float my0 = ((unsigned)y0       < (unsigned)H_) ? 1.f : 0.f;
    float my1 = ((unsigned)(y0 + 1) < (unsigned)H_) ? 1.f : 0.f;
    int x0c = min(max(x0, 0), W_ - 1), x1c = min(max(x0 + 1, 0), W_ - 1);
    int y0c = min(max(y0, 0), H_ - 1), y1c = min(max(y0 + 1, 0), H_ - 1);
    idx[0] = y0c * W_ + x0c; wgt[0] = wy0 * wx0 * my0 * mx0;
    idx[1] = y0c * W_ + x1c; wgt[1] = wy0 * wx1 * my0 * mx1;
    idx[2] = y1c * W_ + x0c; wgt[2] = wy1 * wx0 * my1 * mx0;
    idx[3] = y1c * W_ + x1c; wgt[3] = wy1 * wx1 * my1 * mx1;
}

// -------- K0: weight prep --------
__global__ __launch_bounds__(256) void reorder_w_kernel(
    const float* __restrict__ w1a, const float* __restrict__ w1b,
    const float* __restrict__ s1, const float* __restrict__ b1,
    const float* __restrict__ m1, const float* __restrict__ v1,
    const float* __restrict__ s2, const float* __restrict__ b2,
    const float* __restrict__ m2, const float* __restrict__ v2,
    const float* __restrict__ w2a, const float* __restrict__ w2b,
    const float* __restrict__ ow,
    unsigned short* __restrict__ wqb, float* __restrict__ beta,
    float* __restrict__ wqd, float* __restrict__ wqo)
{
    int tid = threadIdx.x;
    for (int i = tid; i < 16384; i += 256) {
        int j    = i & 7;
        int quad = (i >> 3) & 3;
        int co   = (i >> 5) & 127;
        int kb   = i >> 12;
        int k    = kb * 32 + quad * 8 + j;
        float wt, inv;
        if (co < 64) {
            wt  = w1a[co * 128 + k];
            inv = s1[co] * rsqrtf(v1[co] + 1e-5f);
        } else {
            wt  = w1b[(co - 64) * 128 + k];
            inv = s2[co - 64] * rsqrtf(v2[co - 64] + 1e-5f);
        }
        wqb[i] = f2bf(wt * inv);
    }
    for (int co = tid; co < 128; co += 256) {
        float inv, be;
        if (co < 64) {
            inv = s1[co] * rsqrtf(v1[co] + 1e-5f);
            be  = b1[co] - m1[co] * inv;
        } else {
            inv = s2[co - 64] * rsqrtf(v2[co - 64] + 1e-5f);
            be  = b2[co - 64] - m2[co - 64] * inv;
        }
        beta[co] = be;
    }
    for (int i = tid; i < 2304; i += 256) {
        int oc  = i & 1;
        int ci  = (i >> 1) & 63;
        int tap = (i >> 7) % 9;
        int br  = i / 1152;
        const float* src = br ? w2b : w2a;
        wqd[i] = src[oc * 576 + ci * 9 + tap];
    }
    for (int i = tid; i < 576; i += 256) {
        int tap = i / 64, ci = i % 64;
        wqo[i] = ow[ci * 9 + tap];
    }
}

// -------- K1: NCHW fp32 -> NHWC bf16 transpose (64 ch) --------
__global__ __launch_bounds__(256) void nchw_to_nhwc_bf16(
    const float* __restrict__ in, unsigned short* __restrict__ out, int hw)
{
    int p = blockIdx.x * 256 + threadIdx.x;
    int n = p / hw, rem = p % hw;
    const float* base = in + (long)n * 64 * hw + rem;
    unsigned o32[32];
    #pragma unroll
    for (int c2 = 0; c2 < 32; ++c2) {
        float v0 = base[(long)(2 * c2) * hw];
        float v1 = base[(long)(2 * c2 + 1) * hw];
        o32[c2] = (unsigned)f2bf(v0) | ((unsigned)f2bf(v1) << 16);
    }
    uint4* dst = reinterpret_cast<uint4*>(out + (long)p * 64);
    #pragma unroll
    for (int q = 0; q < 8; ++q)
        dst[q] = make_uint4(o32[q * 4], o32[q * 4 + 1], o32[q * 4 + 2], o32[q * 4 + 3]);
}

// -------- K2: bilinear resize 80->160 (align_corners=True) in NHWC bf16 -----
__global__ __launch_bounds__(256) void resize_high_nhwc(
    const unsigned short* __restrict__ hsb, unsigned short* __restrict__ highb)
{
    int p = blockIdx.x * 256 + threadIdx.x;
    int n = p / HW_, rem = p % HW_;
    int y = rem / W_, x = rem % W_;
    float sx = (x * 79.0f) / 159.0f;
    float sy = (y * 79.0f) / 159.0f;
    int ix0 = (int)sx, iy0 = (int)sy;
    float fx = sx - (float)ix0, fy = sy - (float)iy0;
    int ix1 = min(ix0 + 1, WH_ - 1), iy1 = min(iy0 + 1, HH_ - 1);
    long b = (long)n * (HH_ * WH_);
    const ushort8v* r00 = (const ushort8v*)(hsb + (b + iy0 * WH_ + ix0) * 64);
    const ushort8v* r01 = (const ushort8v*)(hsb + (b + iy0 * WH_ + ix1) * 64);
    const ushort8v* r10 = (const ushort8v*)(hsb + (b + iy1 * WH_ + ix0) * 64);
    const ushort8v* r11 = (const ushort8v*)(hsb + (b + iy1 * WH_ + ix1) * 64);
    float w00 = (1.f - fx) * (1.f - fy), w01 = fx * (1.f - fy);
    float w10 = (1.f - fx) * fy,         w11 = fx * fy;

    float acc[64];
    #pragma unroll
    for (int c = 0; c < 64; ++c) acc[c] = 0.f;
    #pragma unroll
    for (int q = 0; q < 8; ++q) {
        ushort8v v0 = r00[q], v1 = r01[q], v2 = r10[q], v3 = r11[q];
        #pragma unroll
        for (int j = 0; j < 8; ++j) {
            acc[q * 8 + j] = bf2f(v0[j]) * w00 + bf2f(v1[j]) * w01
                           + bf2f(v2[j]) * w10 + bf2f(v3[j]) * w11;
        }
    }
    unsigned o32[32];
    #pragma unroll
    for (int c2 = 0; c2 < 32; ++c2)
        o32[c2] = (unsigned)f2bf(acc[2 * c2]) | ((unsigned)f2bf(acc[2 * c2 + 1]) << 16);
    uint4* dst = reinterpret_cast<uint4*>(highb + (long)p * 64);
    #pragma unroll
    for (int q = 0; q < 8; ++q)
        dst[q] = make_uint4(o32[q * 4], o32[q * 4 + 1], o32[q * 4 + 2], o32[q * 4 + 3]);
}

// -------- K3: FUSED conv1x1(MFMA)+BN -> LDS -> conv3x3 -> d1,d2 --------
// Tile 16x8 output, halo 18x10 = 180 px. 256 threads (4 waves).
// SWAPPED MFMA: D[co][pixel] -> lane holds 4 consecutive co for ONE pixel
// -> vectorized 8B LDS writes into the swizzled [pix][ci] layout.
__global__ __launch_bounds__(256) void fused13_kernel(
    const unsigned short* __restrict__ lowb, const unsigned short* __restrict__ highb,
    const unsigned short* __restrict__ wqb, const float* __restrict__ beta,
    const float* __restrict__ wqd, float* __restrict__ d1, float* __restrict__ d2)
{
    __shared__ unsigned char lds[2 * 180 * 128];   // 46,080 B
    int b  = blockIdx.x;                  // 1600
    int n  = b / 200;
    int t  = b % 200;
    int ty = t / 10, tx = t % 10;         // 20 x 10 tiles of 8x16
    int y0 = ty * 8, x0 = tx * 16;
    int tid  = threadIdx.x;
    int lane = tid & 63;
    int wv   = tid >> 6;
    int r16  = lane & 15;
    int quad = lane >> 4;
    long nb = (long)n * HW_;

    // ---- phase 1: 12 px-groups of 16 (180 valid), wave wv does g = wv+4j ----
    #pragma unroll
    for (int j = 0; j < 3; ++j) {
        int g   = wv + 4 * j;
        int hp0 = g * 16 + r16;
        int hp  = min(hp0, 179);
        int py = hp / 18, px = hp - py * 18;
        int gyc = min(max(y0 + py - 1, 0), H_ - 1);
        int gxc = min(max(x0 + px - 1, 0), W_ - 1);
        long prow = nb + gyc * W_ + gxc;

        const bf16x8* lr = (const bf16x8*)(lowb  + prow * 64);
        const bf16x8* hr = (const bf16x8*)(highb + prow * 64);
        bf16x8 afrag[4];
        afrag[0] = lr[quad];
        afrag[1] = lr[4 + quad];
        afrag[2] = hr[quad];
        afrag[3] = hr[4 + quad];

        f32x4 acc[8];
        #pragma unroll
        for (int ct = 0; ct < 8; ++ct) acc[ct] = (f32x4){0.f, 0.f, 0.f, 0.f};
        #pragma unroll
        for (int kb = 0; kb < 4; ++kb) {
            #pragma unroll
            for (int ct = 0; ct < 8; ++ct) {
                int co = ct * 16 + r16;
                bf16x8 bfr = *reinterpret_cast<const bf16x8*>(
                    wqb + (((kb * 128 + co) * 4 + quad) << 3));
                // SWAP: weights as A (row=co), pixels as B (col=pixel)
                acc[ct] = __builtin_amdgcn_mfma_f32_16x16x32_bf16(
                    bfr, afrag[kb], acc[ct], 0, 0, 0);
            }
        }
        if (hp0 < 180) {
            #pragma unroll
            for (int ct = 0; ct < 8; ++ct) {
                int cob = ct * 16 + quad * 4;          // global co of reg 0
                float4 bet = *reinterpret_cast<const float4*>(beta + cob);
                unsigned lo = (unsigned)f2bf(acc[ct][0] + bet.x)
                            | ((unsigned)f2bf(acc[ct][1] + bet.y) << 16);
                unsigned hi = (unsigned)f2bf(acc[ct][2] + bet.z)
                            | ((unsigned)f2bf(acc[ct][3] + bet.w) << 16);
                int brof = (ct < 4) ? 0 : 23040;
                int cc2  = ((ct & 3) * 16 + quad * 4) * 2;   // byte off within row
                int byte = brof + ((hp0 * 128 + cc2) ^ ((hp0 & 7) << 4));
                *reinterpret_cast<uint2*>(lds + byte) = make_uint2(lo, hi);
            }
        }
    }
    __syncthreads();

    // ---- phase 2: conv3x3 from LDS; unit = (branch, pixel) ----
    int br  = tid >> 7;          // 0/1
    int pxl = tid & 127;         // 128 output px
    int oy = pxl >> 4, ox = pxl & 15;
    int gy = y0 + oy, gx = x0 + ox;
    const float* wbase = wqd + br * 1152;
    const unsigned char* lbase = lds + br * 23040;

    float a0 = 0.f, a1 = 0.f;
    #pragma unroll
    for (int ky = 0; ky < 3; ++ky) {
        int yy = gy + ky - 1;
        float ym = ((unsigned)yy < (unsigned)H_) ? 1.f : 0.f;
        #pragma unroll
        for (int kx = 0; kx < 3; ++kx) {
            int xx = gx + kx - 1;
            float m = (((unsigned)xx < (unsigned)W_) ? 1.f : 0.f) * ym;
            int pix = (oy + ky) * 18 + (ox + kx);
            const float* wp = wbase + (ky * 3 + kx) * 128;
            float p0 = 0.f, p1 = 0.f;
            #pragma unroll
            for (int qq = 0; qq < 8; ++qq) {
                ushort8v v = *reinterpret_cast<const ushort8v*>(
                    lbase + ((pix * 128 + qq * 16) ^ ((pix & 7) << 4)));
                #pragma unroll
                for (int k = 0; k < 8; ++k) {
                    float fv = bf2f(v[k]);
                    p0 = fmaf(fv, wp[(qq * 8 + k) * 2 + 0], p0);
                    p1 = fmaf(fv, wp[(qq * 8 + k) * 2 + 1], p1);
                }
            }
            a0 = fmaf(m, p0, a0);
            a1 = fmaf(m, p1, a1);
        }
    }
    float* dst = br ? d2 : d1;
    *reinterpret_cast<float2*>(dst + (nb + gy * W_ + gx) * 2) = make_float2(a0, a1);
}

// -------- K4: warp+combine, channel-split (2 thr/px), imap inline --------
__global__ __launch_bounds__(256) void warp_combine_cs(
    const unsigned short* __restrict__ lowb, const unsigned short* __restrict__ highb,
    const float* __restrict__ d1, const float* __restrict__ d2,
    const float* __restrict__ imin, const float* __restrict__ gamma,
    float* __restrict__ f, unsigned short* __restrict__ fnb)
{
    int u = blockIdx.x * 256 + threadIdx.x;   // over 2*PSZ_
    int p = u >> 1, half = u & 1;
    int n = p / HW_, rem = p % HW_;
    int y = rem / W_, x = rem % W_;
    long nb = (long)n * HW_;

    float bgx = -1.f + x * (2.f / 159.f);
    float bgy = -1.f + y * (2.f / 159.f);

    float2 dv1 = *reinterpret_cast<const float2*>(d1 + (long)p * 2);
    float2 dv2 = *reinterpret_cast<const float2*>(d2 + (long)p * 2);

    int idx1[4], idx2[4];
    float wgt1[4], wgt2[4];
    gs_setup(bgx, bgy, dv1.x, dv1.y, idx1, wgt1);
    gs_setup(bgx, bgy, dv2.x, dv2.y, idx2, wgt2);

    // imap inline: bilinear(in_map, align_corners=True) + sigmoid
    float s;
    {
        float sx = (x * 79.0f) / 159.0f;
        float sy = (y * 79.0f) / 159.0f;
        int ix0 = (int)sx, iy0 = (int)sy;
        float fx = sx - (float)ix0, fy = sy - (float)iy0;
        int ix1 = min(ix0 + 1, WH_ - 1), iy1 = min(iy0 + 1, HH_ - 1);
        const float* ip = imin + n * (HH_ * WH_);
        float v00 = ip[iy0 * WH_ + ix0], v01 = ip[iy0 * WH_ + ix1];
        float v10 = ip[iy1 * WH_ + ix0], v11 = ip[iy1 * WH_ + ix1];
        float v = (v00 * (1.f - fx) + v01 * fx) * (1.f - fy)
                + (v10 * (1.f - fx) + v11 * fx) * fy;
        s = 1.f + gamma[0] * (1.f / (1.f + expf(-v)));
    }

    float acc[32];
    #pragma unroll
    for (int c = 0; c < 32; ++c) acc[c] = 0.f;

    #pragma unroll
    for (int j = 0; j < 4; ++j) {
        const ushort8v* row = (const ushort8v*)(highb + (nb + idx1[j]) * 64 + half * 32);
        float w = wgt1[j];
        #pragma unroll
        for (int q = 0; q < 4; ++q) {
            ushort8v v = row[q];
            #pragma unroll
            for (int k = 0; k < 8; ++k)
                acc[q * 8 + k] = fmaf(bf2f(v[k]), w, acc[q * 8 + k]);
        }
    }
    #pragma unroll
    for (int j = 0; j < 4; ++j) {
        const ushort8v* row = (const ushort8v*)(lowb + (nb + idx2[j]) * 64 + half * 32);
        float w = wgt2[j];
        #pragma unroll
        for (int q = 0; q < 4; ++q) {
            ushort8v v = row[q];
            #pragma unroll
            for (int k = 0; k < 8; ++k)
                acc[q * 8 + k] = fmaf(bf2f(v[k]), w, acc[q * 8 + k]);
        }
    }

    float* fp = f + nb * 64 + (long)(half * 32) * HW_ + rem;
    unsigned o32[16];
    #pragma unroll
    for (int c2 = 0; c2 < 16; ++c2) {
        float f0 = acc[2 * c2]     * s;
        float f1 = acc[2 * c2 + 1] * s;
        fp[(long)(2 * c2) * HW_]     = f0;
        fp[(long)(2 * c2 + 1) * HW_] = f1;
        o32[c2] = (unsigned)f2bf(f0) | ((unsigned)f2bf(f1) << 16);
    }
    uint4* dst = reinterpret_cast<uint4*>(fnb + (long)p * 64 + half * 32);
    #pragma unroll
    for (int q = 0; q < 4; ++q)
        dst[q] = make_uint4(o32[q * 4], o32[q * 4 + 1], o32[q * 4 + 2], o32[q * 4 + 3]);
}

// -------- K5: conv3x3 pad=1, bf16 NHWC 64->1 + bias, LDS-tiled --------
__global__ __launch_bounds__(256) void out_conv_tiled(
    const unsigned short* __restrict__ fnb, const float* __restrict__ wqo,
    const float* __restrict__ ob, float* __restrict__ o)
{
    __shared__ unsigned char lds[324 * 128];
    int b  = blockIdx.x;                   // 0..799
    int n  = b / 100;
    int t  = b % 100;
    int ty = t / 10, tx = t % 10;
    int y0 = ty * 16 - 1, x0 = tx * 16 - 1;
    int tid = threadIdx.x;

    for (int i = tid; i < 324 * 8; i += 256) {
        int pix = i >> 3, qq = i & 7;
        int py = pix / 18, px = pix % 18;
        int yy = min(max(y0 + py, 0), H_ - 1);
        int xx = min(max(x0 + px, 0), W_ - 1);
        ushort8v v = *reinterpret_cast<const ushort8v*>(
            fnb + ((long)(n * HW_ + yy * W_ + xx)) * 64 + qq * 8);
        *reinterpret_cast<ushort8v*>(
            lds + ((pix * 128 + qq * 16) ^ ((pix & 7) << 4))) = v;
    }
    __syncthreads();

    int oy = tid >> 4, ox = tid & 15;
    int gy = ty * 16 + oy, gx = tx * 16 + ox;

    float acc = 0.f;
    #pragma unroll
    for (int ky = 0; ky < 3; ++ky) {
        int yy = gy + ky - 1;
        float ym = ((unsigned)yy < (unsigned)H_) ? 1.f : 0.f;
        #pragma unroll
        for (int kx = 0; kx < 3; ++kx) {
            int xx = gx + kx - 1;
            float m = (((unsigned)xx < (unsigned)W_) ? 1.f : 0.f) * ym;
            int pix = (oy + ky) * 18 + (ox + kx);
            const float* wp = wqo + (ky * 3 + kx) * 64;
            float part = 0.f;
            #pragma unroll
            for (int qq = 0; qq < 8; ++qq) {
                ushort8v v = *reinterpret_cast<const ushort8v*>(
                    lds + ((pix * 128 + qq * 16) ^ ((pix & 7) << 4)));
                #pragma unroll
                for (int k = 0; k < 8; ++k)
                    part = fmaf(bf2f(v[k]), wp[qq * 8 + k], part);
            }
            acc = fmaf(m, part, acc);
        }
    }
    o[n * HW_ + gy * W_ + gx] = acc + ob[0];
}

extern "C" void kernel_launch(void* const* d_in, const int* in_sizes, int n_in,
                              void* d_out, int out_size, void* d_ws, size_t ws_size,
                              hipStream_t stream) {
    const float* low    = (const float*)d_in[0];
    const float* hsin   = (const float*)d_in[1];
    const float* imin   = (const float*)d_in[2];
    const float* dg1_w1 = (const float*)d_in[3];
    const float* dg1_s  = (const float*)d_in[4];
    const float* dg1_b  = (const float*)d_in[5];
    const float* dg1_m  = (const float*)d_in[6];
    const float* dg1_v  = (const float*)d_in[7];
    const float* dg1_w2 = (const float*)d_in[8];
    const float* dg2_w1 = (const float*)d_in[9];
    const float* dg2_s  = (const float*)d_in[10];
    const float* dg2_b  = (const float*)d_in[11];
    const float* dg2_m  = (const float*)d_in[12];
    const float* dg2_v  = (const float*)d_in[13];
    const float* dg2_w2 = (const float*)d_in[14];
    const float* gamma  = (const float*)d_in[15];
    const float* out_w  = (const float*)d_in[16];
    const float* out_b  = (const float*)d_in[17];

    float* ws   = (float*)d_ws;
    float* d1   = ws;                           // 2*PSZ_
    float* d2   = d1 + 2 * PSZ_;                // 2*PSZ_
    float* wqd  = d2 + 2 * PSZ_;                // 2304
    float* wqo  = wqd + 2304;                   // 576
    float* beta = wqo + 576;                    // 128
    unsigned short* wqb   = (unsigned short*)(beta + 128);  // 16384
    unsigned short* lowb  = wqb + 16384;        // FSZ_ bf16 NHWC
    unsigned short* highb = lowb + FSZ_;        // FSZ_ bf16 NHWC
    unsigned short* fnb   = highb + FSZ_;       // FSZ_ bf16 NHWC
    unsigned short* hsb   = fnb;                // alias: hsb dead before fnb written

    float* fout = (float*)d_out;                // FSZ_ (output 0, NCHW fp32)
    float* oout = fout + FSZ_;                  // PSZ_ (output 1)

    reorder_w_kernel<<<1, 256, 0, stream>>>(
        dg1_w1, dg2_w1, dg1_s, dg1_b, dg1_m, dg1_v,
        dg2_s, dg2_b, dg2_m, dg2_v, dg1_w2, dg2_w2, out_w,
        wqb, beta, wqd, wqo);
    nchw_to_nhwc_bf16<<<PSZ_ / 256, 256, 0, stream>>>(low, lowb, HW_);
    nchw_to_nhwc_bf16<<<(N_ * HH_ * WH_) / 256, 256, 0, stream>>>(hsin, hsb, HH_ * WH_);
    resize_high_nhwc<<<PSZ_ / 256, 256, 0, stream>>>(hsb, highb);
    fused13_kernel<<<1600, 256, 0, stream>>>(
        lowb, highb, wqb, beta, wqd, d1, d2);
    warp_combine_cs<<<PSZ_ * 2 / 256, 256, 0, stream>>>(
        lowb, highb, d1, d2, imin, gamma, fout, fnb);
    out_conv_tiled<<<800, 256, 0, stream>>>(fnb, wqo, out_b, oout);
}

// Round 9
// 219.598 us; speedup vs baseline: 1.1370x; 1.1370x over previous
//
#include <hip/hip_runtime.h>
#include <cmath>

#define N_   8
#define C_   64
#define H_   160
#define W_   160
#define HW_  25600
#define HH_  80
#define WH_  80
#define FSZ_ (N_ * C_ * HW_)   // 13,107,200
#define PSZ_ (N_ * HW_)        // 204,800

typedef unsigned short ushort8v __attribute__((ext_vector_type(8)));
typedef short          bf16x8  __attribute__((ext_vector_type(8)));
typedef float          f32x4   __attribute__((ext_vector_type(4)));

__device__ __forceinline__ float bf2f(unsigned short u) {
    return __uint_as_float(((unsigned)u) << 16);
}
__device__ __forceinline__ unsigned short f2bf(float f) {
    unsigned u = __float_as_uint(f);
    u += 0x7FFF + ((u >> 16) & 1);          // RNE
    return (unsigned short)(u >> 16);
}

// grid-sample setup: 4 tap indices + weights (align_corners=False, zeros pad)
__device__ __forceinline__ void gs_setup(float bgx, float bgy, float dx, float dy,
                                         int* idx, float* wgt)
{
    float px = ((bgx + dx * (1.f / 160.f)) + 1.f) * 80.f - 0.5f;
    float py = ((bgy + dy * (1.f / 160.f)) + 1.f) * 80.f - 0.5f;
    float x0f = floorf(px), y0f = floorf(py);
    float wx1 = px - x0f, wy1 = py - y0f, wx0 = 1.f - wx1, wy0 = 1.f - wy1;
    int x0 = (int)x0f, y0 = (int)y0f;
    float mx0 = ((unsigned)x0       < (unsigned)W_) ? 1.f : 0.f;
    float mx1 = ((unsigned)(x0 + 1) < (unsigned)W_) ? 1.f : 0.f;
    float my0 = ((unsigned)y0       < (unsigned)H_) ? 1.f : 0.f;
    float my1 = ((unsigned)(y0 + 1) < (unsigned)H_) ? 1.f : 0.f;
    int x0c = min(max(x0, 0), W_ - 1), x1c = min(max(x0 + 1, 0), W_ - 1);
    int y0c = min(max(y0, 0), H_ - 1), y1c = min(max(y0 + 1, 0), H_ - 1);
    idx[0] = y0c * W_ + x0c; wgt[0] = wy0 * wx0 * my0 * mx0;
    idx[1] = y0c * W_ + x1c; wgt[1] = wy0 * wx1 * my0 * mx1;
    idx[2] = y1c * W_ + x0c; wgt[2] = wy1 * wx0 * my1 * mx0;
    idx[3] = y1c * W_ + x1c; wgt[3] = wy1 * wx1 * my1 * mx1;
}

// -------- K0: weight prep --------
// wqb : conv1 weights*BNscale, MFMA B-layout (kb,co,quad,j)         [bf16]
// beta: BN beta                                                     [f32]
// wA  : conv3 d-weights, MFMA A-fragment table                      [bf16]
//       idx = ((br*9+tap)*2+s)*512 + lane*8 + j ; row=lane&15 (>=2 -> 0),
//       ci = s*32 + (lane>>4)*8 + j
// wqo : out conv3 weights [tap][ci]                                 [f32]
__global__ __launch_bounds__(256) void reorder_w_kernel(
    const float* __restrict__ w1a, const float* __restrict__ w1b,
    const float* __restrict__ s1, const float* __restrict__ b1,
    const float* __restrict__ m1, const float* __restrict__ v1,
    const float* __restrict__ s2, const float* __restrict__ b2,
    const float* __restrict__ m2, const float* __restrict__ v2,
    const float* __restrict__ w2a, const float* __restrict__ w2b,
    const float* __restrict__ ow,
    unsigned short* __restrict__ wqb, float* __restrict__ beta,
    unsigned short* __restrict__ wA, float* __restrict__ wqo)
{
    int tid = threadIdx.x;
    for (int i = tid; i < 16384; i += 256) {
        int j    = i & 7;
        int quad = (i >> 3) & 3;
        int co   = (i >> 5) & 127;
        int kb   = i >> 12;
        int k    = kb * 32 + quad * 8 + j;
        float wt, inv;
        if (co < 64) {
            wt  = w1a[co * 128 + k];
            inv = s1[co] * rsqrtf(v1[co] + 1e-5f);
        } else {
            wt  = w1b[(co - 64) * 128 + k];
            inv = s2[co - 64] * rsqrtf(v2[co - 64] + 1e-5f);
        }
        wqb[i] = f2bf(wt * inv);
    }
    for (int co = tid; co < 128; co += 256) {
        float inv, be;
        if (co < 64) {
            inv = s1[co] * rsqrtf(v1[co] + 1e-5f);
            be  = b1[co] - m1[co] * inv;
        } else {
            inv = s2[co - 64] * rsqrtf(v2[co - 64] + 1e-5f);
            be  = b2[co - 64] - m2[co - 64] * inv;
        }
        beta[co] = be;
    }
    for (int i = tid; i < 18432; i += 256) {
        int j    = i & 7;
        int lane = (i >> 3) & 63;
        int s    = (i >> 9) & 1;
        int t2   = i >> 10;
        int tap  = t2 % 9;
        int br   = t2 / 9;
        int row  = lane & 15;
        int ci   = s * 32 + (lane >> 4) * 8 + j;
        const float* src = br ? w2b : w2a;
        float v = (row < 2) ? src[row * 576 + ci * 9 + tap] : 0.f;
        wA[i] = f2bf(v);
    }
    for (int i = tid; i < 576; i += 256) {
        int tap = i / 64, ci = i % 64;
        wqo[i] = ow[ci * 9 + tap];
    }
}

// -------- K1: NCHW fp32 -> NHWC bf16 transpose (64 ch) --------
__global__ __launch_bounds__(256) void nchw_to_nhwc_bf16(
    const float* __restrict__ in, unsigned short* __restrict__ out, int hw)
{
    int p = blockIdx.x * 256 + threadIdx.x;
    int n = p / hw, rem = p % hw;
    const float* base = in + (long)n * 64 * hw + rem;
    unsigned o32[32];
    #pragma unroll
    for (int c2 = 0; c2 < 32; ++c2) {
        float v0 = base[(long)(2 * c2) * hw];
        float v1 = base[(long)(2 * c2 + 1) * hw];
        o32[c2] = (unsigned)f2bf(v0) | ((unsigned)f2bf(v1) << 16);
    }
    uint4* dst = reinterpret_cast<uint4*>(out + (long)p * 64);
    #pragma unroll
    for (int q = 0; q < 8; ++q)
        dst[q] = make_uint4(o32[q * 4], o32[q * 4 + 1], o32[q * 4 + 2], o32[q * 4 + 3]);
}

// -------- K2: bilinear resize 80->160 (align_corners=True) in NHWC bf16 -----
__global__ __launch_bounds__(256) void resize_high_nhwc(
    const unsigned short* __restrict__ hsb, unsigned short* __restrict__ highb)
{
    int p = blockIdx.x * 256 + threadIdx.x;
    int n = p / HW_, rem = p % HW_;
    int y = rem / W_, x = rem % W_;
    float sx = (x * 79.0f) / 159.0f;
    float sy = (y * 79.0f) / 159.0f;
    int ix0 = (int)sx, iy0 = (int)sy;
    float fx = sx - (float)ix0, fy = sy - (float)iy0;
    int ix1 = min(ix0 + 1, WH_ - 1), iy1 = min(iy0 + 1, HH_ - 1);
    long b = (long)n * (HH_ * WH_);
    const ushort8v* r00 = (const ushort8v*)(hsb + (b + iy0 * WH_ + ix0) * 64);
    const ushort8v* r01 = (const ushort8v*)(hsb + (b + iy0 * WH_ + ix1) * 64);
    const ushort8v* r10 = (const ushort8v*)(hsb + (b + iy1 * WH_ + ix0) * 64);
    const ushort8v* r11 = (const ushort8v*)(hsb + (b + iy1 * WH_ + ix1) * 64);
    float w00 = (1.f - fx) * (1.f - fy), w01 = fx * (1.f - fy);
    float w10 = (1.f - fx) * fy,         w11 = fx * fy;

    float acc[64];
    #pragma unroll
    for (int c = 0; c < 64; ++c) acc[c] = 0.f;
    #pragma unroll
    for (int q = 0; q < 8; ++q) {
        ushort8v v0 = r00[q], v1 = r01[q], v2 = r10[q], v3 = r11[q];
        #pragma unroll
        for (int j = 0; j < 8; ++j) {
            acc[q * 8 + j] = bf2f(v0[j]) * w00 + bf2f(v1[j]) * w01
                           + bf2f(v2[j]) * w10 + bf2f(v3[j]) * w11;
        }
    }
    unsigned o32[32];
    #pragma unroll
    for (int c2 = 0; c2 < 32; ++c2)
        o32[c2] = (unsigned)f2bf(acc[2 * c2]) | ((unsigned)f2bf(acc[2 * c2 + 1]) << 16);
    uint4* dst = reinterpret_cast<uint4*>(highb + (long)p * 64);
    #pragma unroll
    for (int q = 0; q < 8; ++q)
        dst[q] = make_uint4(o32[q * 4], o32[q * 4 + 1], o32[q * 4 + 2], o32[q * 4 + 3]);
}

// -------- K3: FUSED conv1x1(MFMA)+BN -> LDS -> conv3x3(MFMA) -> d1,d2 --------
// Tile 8x16 output, halo 10x18 = 180 px. 256 threads (4 waves).
// Phase 1: t1,t2 on halo via swapped MFMA (D[co][pix]) -> swizzled LDS bf16,
//          zeros for out-of-image halo (conv zero-padding).
// Phase 2: conv3x3 via MFMA: A = weight fragments (rows 0-1 = oc), B = LDS rows.
__global__ __launch_bounds__(256) void fused13_kernel(
    const unsigned short* __restrict__ lowb, const unsigned short* __restrict__ highb,
    const unsigned short* __restrict__ wqb, const float* __restrict__ beta,
    const unsigned short* __restrict__ wA, float* __restrict__ d1,
    float* __restrict__ d2)
{
    __shared__ unsigned char lds[2 * 180 * 128];   // 46,080 B
    int b  = blockIdx.x;                  // 1600
    int n  = b / 200;
    int t  = b % 200;
    int ty = t / 10, tx = t % 10;         // 20 x 10 tiles of 8x16
    int y0 = ty * 8, x0 = tx * 16;
    int tid  = threadIdx.x;
    int lane = tid & 63;
    int wv   = tid >> 6;
    int r16  = lane & 15;
    int quad = lane >> 4;
    long nb = (long)n * HW_;

    // ---- phase 1: 12 px-groups of 16 (180 valid), wave wv does g = wv+4j ----
    #pragma unroll
    for (int j = 0; j < 3; ++j) {
        int g   = wv + 4 * j;
        int hp0 = g * 16 + r16;
        int hp  = min(hp0, 179);
        int py = hp / 18, px = hp - py * 18;
        int yy = y0 + py - 1, xx = x0 + px - 1;
        float vm = (((unsigned)yy < (unsigned)H_) && ((unsigned)xx < (unsigned)W_))
                 ? 1.f : 0.f;                       // conv zero-padding
        int gyc = min(max(yy, 0), H_ - 1);
        int gxc = min(max(xx, 0), W_ - 1);
        long prow = nb + gyc * W_ + gxc;

        const bf16x8* lr = (const bf16x8*)(lowb  + prow * 64);
        const bf16x8* hr = (const bf16x8*)(highb + prow * 64);
        bf16x8 afrag[4];
        afrag[0] = lr[quad];
        afrag[1] = lr[4 + quad];
        afrag[2] = hr[quad];
        afrag[3] = hr[4 + quad];

        f32x4 acc[8];
        #pragma unroll
        for (int ct = 0; ct < 8; ++ct) acc[ct] = (f32x4){0.f, 0.f, 0.f, 0.f};
        #pragma unroll
        for (int kb = 0; kb < 4; ++kb) {
            #pragma unroll
            for (int ct = 0; ct < 8; ++ct) {
                int co = ct * 16 + r16;
                bf16x8 bfr = *reinterpret_cast<const bf16x8*>(
                    wqb + (((kb * 128 + co) * 4 + quad) << 3));
                // swapped: weights as A (row=co), pixels as B (col=pixel)
                acc[ct] = __builtin_amdgcn_mfma_f32_16x16x32_bf16(
                    bfr, afrag[kb], acc[ct], 0, 0, 0);
            }
        }
        if (hp0 < 180) {
            #pragma unroll
            for (int ct = 0; ct < 8; ++ct) {
                int cob = ct * 16 + quad * 4;          // global co of reg 0
                float4 bet = *reinterpret_cast<const float4*>(beta + cob);
                unsigned lo = (unsigned)f2bf((acc[ct][0] + bet.x) * vm)
                            | ((unsigned)f2bf((acc[ct][1] + bet.y) * vm) << 16);
                unsigned hi = (unsigned)f2bf((acc[ct][2] + bet.z) * vm)
                            | ((unsigned)f2bf((acc[ct][3] + bet.w) * vm) << 16);
                int brof = (ct < 4) ? 0 : 23040;
                int cc2  = ((ct & 3) * 16 + quad * 4) * 2;   // byte off in row
                int byte = brof + ((hp0 * 128 + cc2) ^ ((hp0 & 7) << 4));
                *reinterpret_cast<uint2*>(lds + byte) = make_uint2(lo, hi);
            }
        }
    }
    __syncthreads();

    // ---- phase 2: conv3x3 via MFMA; wave wv owns output rows wv, wv+4 ----
    f32x4 a1[2], a2[2];
    a1[0] = a1[1] = a2[0] = a2[1] = (f32x4){0.f, 0.f, 0.f, 0.f};

    #pragma unroll
    for (int tap = 0; tap < 9; ++tap) {
        int ky = tap / 3, kx = tap % 3;
        bf16x8 A10 = *reinterpret_cast<const bf16x8*>(
            wA + (((0 * 9 + tap) * 2 + 0) << 9) + lane * 8);
        bf16x8 A11 = *reinterpret_cast<const bf16x8*>(
            wA + (((0 * 9 + tap) * 2 + 1) << 9) + lane * 8);
        bf16x8 A20 = *reinterpret_cast<const bf16x8*>(
            wA + (((1 * 9 + tap) * 2 + 0) << 9) + lane * 8);
        bf16x8 A21 = *reinterpret_cast<const bf16x8*>(
            wA + (((1 * 9 + tap) * 2 + 1) << 9) + lane * 8);
        #pragma unroll
        for (int g = 0; g < 2; ++g) {
            int oy = wv + g * 4;
            int tp = (oy + ky) * 18 + r16 + kx;
            int sw = (tp & 7) << 4;
            bf16x8 B10 = *reinterpret_cast<const bf16x8*>(
                lds + ((tp * 128 + quad * 16) ^ sw));
            bf16x8 B11 = *reinterpret_cast<const bf16x8*>(
                lds + ((tp * 128 + 64 + quad * 16) ^ sw));
            bf16x8 B20 = *reinterpret_cast<const bf16x8*>(
                lds + 23040 + ((tp * 128 + quad * 16) ^ sw));
            bf16x8 B21 = *reinterpret_cast<const bf16x8*>(
                lds + 23040 + ((tp * 128 + 64 + quad * 16) ^ sw));
            a1[g] = __builtin_amdgcn_mfma_f32_16x16x32_bf16(A10, B10, a1[g], 0, 0, 0);
            a1[g] = __builtin_amdgcn_mfma_f32_16x16x32_bf16(A11, B11, a1[g], 0, 0, 0);
            a2[g] = __builtin_amdgcn_mfma_f32_16x16x32_bf16(A20, B20, a2[g], 0, 0, 0);
            a2[g] = __builtin_amdgcn_mfma_f32_16x16x32_bf16(A21, B21, a2[g], 0, 0, 0);
        }
    }
    if (quad == 0) {
        #pragma unroll
        for (int g = 0; g < 2; ++g) {
            int oy = wv + g * 4;
            long p = nb + (y0 + oy) * W_ + x0 + r16;
            *reinterpret_cast<float2*>(d1 + p * 2) = make_float2(a1[g][0], a1[g][1]);
            *reinterpret_cast<float2*>(d2 + p * 2) = make_float2(a2[g][0], a2[g][1]);
        }
    }
}

// -------- K4: warp+combine, channel-split (2 thr/px), imap inline --------
__global__ __launch_bounds__(256) void warp_combine_cs(
    const unsigned short* __restrict__ lowb, const unsigned short* __restrict__ highb,
    const float* __restrict__ d1, const float* __restrict__ d2,
    const float* __restrict__ imin, const float* __restrict__ gamma,
    float* __restrict__ f, unsigned short* __restrict__ fnb)
{
    int u = blockIdx.x * 256 + threadIdx.x;   // over 2*PSZ_
    int p = u >> 1, half = u & 1;
    int n = p / HW_, rem = p % HW_;
    int y = rem / W_, x = rem % W_;
    long nb = (long)n * HW_;

    float bgx = -1.f + x * (2.f / 159.f);
    float bgy = -1.f + y * (2.f / 159.f);

    float2 dv1 = *reinterpret_cast<const float2*>(d1 + (long)p * 2);
    float2 dv2 = *reinterpret_cast<const float2*>(d2 + (long)p * 2);

    int idx1[4], idx2[4];
    float wgt1[4], wgt2[4];
    gs_setup(bgx, bgy, dv1.x, dv1.y, idx1, wgt1);
    gs_setup(bgx, bgy, dv2.x, dv2.y, idx2, wgt2);

    // imap inline: bilinear(in_map, align_corners=True) + sigmoid
    float s;
    {
        float sx = (x * 79.0f) / 159.0f;
        float sy = (y * 79.0f) / 159.0f;
        int ix0 = (int)sx, iy0 = (int)sy;
        float fx = sx - (float)ix0, fy = sy - (float)iy0;
        int ix1 = min(ix0 + 1, WH_ - 1), iy1 = min(iy0 + 1, HH_ - 1);
        const float* ip = imin + n * (HH_ * WH_);
        float v00 = ip[iy0 * WH_ + ix0], v01 = ip[iy0 * WH_ + ix1];
        float v10 = ip[iy1 * WH_ + ix0], v11 = ip[iy1 * WH_ + ix1];
        float v = (v00 * (1.f - fx) + v01 * fx) * (1.f - fy)
                + (v10 * (1.f - fx) + v11 * fx) * fy;
        s = 1.f + gamma[0] * (1.f / (1.f + expf(-v)));
    }

    float acc[32];
    #pragma unroll
    for (int c = 0; c < 32; ++c) acc[c] = 0.f;

    #pragma unroll
    for (int j = 0; j < 4; ++j) {
        const ushort8v* row = (const ushort8v*)(highb + (nb + idx1[j]) * 64 + half * 32);
        float w = wgt1[j];
        #pragma unroll
        for (int q = 0; q < 4; ++q) {
            ushort8v v = row[q];
            #pragma unroll
            for (int k = 0; k < 8; ++k)
                acc[q * 8 + k] = fmaf(bf2f(v[k]), w, acc[q * 8 + k]);
        }
    }
    #pragma unroll
    for (int j = 0; j < 4; ++j) {
        const ushort8v* row = (const ushort8v*)(lowb + (nb + idx2[j]) * 64 + half * 32);
        float w = wgt2[j];
        #pragma unroll
        for (int q = 0; q < 4; ++q) {
            ushort8v v = row[q];
            #pragma unroll
            for (int k = 0; k < 8; ++k)
                acc[q * 8 + k] = fmaf(bf2f(v[k]), w, acc[q * 8 + k]);
        }
    }

    float* fp = f + nb * 64 + (long)(half * 32) * HW_ + rem;
    unsigned o32[16];
    #pragma unroll
    for (int c2 = 0; c2 < 16; ++c2) {
        float f0 = acc[2 * c2]     * s;
        float f1 = acc[2 * c2 + 1] * s;
        fp[(long)(2 * c2) * HW_]     = f0;
        fp[(long)(2 * c2 + 1) * HW_] = f1;
        o32[c2] = (unsigned)f2bf(f0) | ((unsigned)f2bf(f1) << 16);
    }
    uint4* dst = reinterpret_cast<uint4*>(fnb + (long)p * 64 + half * 32);
    #pragma unroll
    for (int q = 0; q < 4; ++q)
        dst[q] = make_uint4(o32[q * 4], o32[q * 4 + 1], o32[q * 4 + 2], o32[q * 4 + 3]);
}

// -------- K5: conv3x3 pad=1, bf16 NHWC 64->1 + bias, LDS-tiled --------
__global__ __launch_bounds__(256) void out_conv_tiled(
    const unsigned short* __restrict__ fnb, const float* __restrict__ wqo,
    const float* __restrict__ ob, float* __restrict__ o)
{
    __shared__ unsigned char lds[324 * 128];
    int b  = blockIdx.x;                   // 0..799
    int n  = b / 100;
    int t  = b % 100;
    int ty = t / 10, tx = t % 10;
    int y0 = ty * 16 - 1, x0 = tx * 16 - 1;
    int tid = threadIdx.x;

    for (int i = tid; i < 324 * 8; i += 256) {
        int pix = i >> 3, qq = i & 7;
        int py = pix / 18, px = pix % 18;
        int yy = min(max(y0 + py, 0), H_ - 1);
        int xx = min(max(x0 + px, 0), W_ - 1);
        ushort8v v = *reinterpret_cast<const ushort8v*>(
            fnb + ((long)(n * HW_ + yy * W_ + xx)) * 64 + qq * 8);
        *reinterpret_cast<ushort8v*>(
            lds + ((pix * 128 + qq * 16) ^ ((pix & 7) << 4))) = v;
    }
    __syncthreads();

    int oy = tid >> 4, ox = tid & 15;
    int gy = ty * 16 + oy, gx = tx * 16 + ox;

    float acc = 0.f;
    #pragma unroll
    for (int ky = 0; ky < 3; ++ky) {
        int yy = gy + ky - 1;
        float ym = ((unsigned)yy < (unsigned)H_) ? 1.f : 0.f;
        #pragma unroll
        for (int kx = 0; kx < 3; ++kx) {
            int xx = gx + kx - 1;
            float m = (((unsigned)xx < (unsigned)W_) ? 1.f : 0.f) * ym;
            int pix = (oy + ky) * 18 + (ox + kx);
            const float* wp = wqo + (ky * 3 + kx) * 64;
            float part = 0.f;
            #pragma unroll
            for (int qq = 0; qq < 8; ++qq) {
                ushort8v v = *reinterpret_cast<const ushort8v*>(
                    lds + ((pix * 128 + qq * 16) ^ ((pix & 7) << 4)));
                #pragma unroll
                for (int k = 0; k < 8; ++k)
                    part = fmaf(bf2f(v[k]), wp[qq * 8 + k], part);
            }
            acc = fmaf(m, part, acc);
        }
    }
    o[n * HW_ + gy * W_ + gx] = acc + ob[0];
}

extern "C" void kernel_launch(void* const* d_in, const int* in_sizes, int n_in,
                              void* d_out, int out_size, void* d_ws, size_t ws_size,
                              hipStream_t stream) {
    const float* low    = (const float*)d_in[0];
    const float* hsin   = (const float*)d_in[1];
    const float* imin   = (const float*)d_in[2];
    const float* dg1_w1 = (const float*)d_in[3];
    const float* dg1_s  = (const float*)d_in[4];
    const float* dg1_b  = (const float*)d_in[5];
    const float* dg1_m  = (const float*)d_in[6];
    const float* dg1_v  = (const float*)d_in[7];
    const float* dg1_w2 = (const float*)d_in[8];
    const float* dg2_w1 = (const float*)d_in[9];
    const float* dg2_s  = (const float*)d_in[10];
    const float* dg2_b  = (const float*)d_in[11];
    const float* dg2_m  = (const float*)d_in[12];
    const float* dg2_v  = (const float*)d_in[13];
    const float* dg2_w2 = (const float*)d_in[14];
    const float* gamma  = (const float*)d_in[15];
    const float* out_w  = (const float*)d_in[16];
    const float* out_b  = (const float*)d_in[17];

    float* ws   = (float*)d_ws;
    float* d1   = ws;                           // 2*PSZ_
    float* d2   = d1 + 2 * PSZ_;                // 2*PSZ_
    float* wqo  = d2 + 2 * PSZ_;                // 576
    float* beta = wqo + 576;                    // 128
    unsigned short* wqb   = (unsigned short*)(beta + 128);  // 16384
    unsigned short* wA    = wqb + 16384;        // 18432
    unsigned short* lowb  = wA + 18432;         // FSZ_ bf16 NHWC
    unsigned short* highb = lowb + FSZ_;        // FSZ_ bf16 NHWC
    unsigned short* fnb   = highb + FSZ_;       // FSZ_ bf16 NHWC
    unsigned short* hsb   = fnb;                // alias: hsb dead before fnb written

    float* fout = (float*)d_out;                // FSZ_ (output 0, NCHW fp32)
    float* oout = fout + FSZ_;                  // PSZ_ (output 1)

    reorder_w_kernel<<<1, 256, 0, stream>>>(
        dg1_w1, dg2_w1, dg1_s, dg1_b, dg1_m, dg1_v,
        dg2_s, dg2_b, dg2_m, dg2_v, dg1_w2, dg2_w2, out_w,
        wqb, beta, wA, wqo);
    nchw_to_nhwc_bf16<<<PSZ_ / 256, 256, 0, stream>>>(low, lowb, HW_);
    nchw_to_nhwc_bf16<<<(N_ * HH_ * WH_) / 256, 256, 0, stream>>>(hsin, hsb, HH_ * WH_);
    resize_high_nhwc<<<PSZ_ / 256, 256, 0, stream>>>(hsb, highb);
    fused13_kernel<<<1600, 256, 0, stream>>>(
        lowb, highb, wqb, beta, wA, d1, d2);
    warp_combine_cs<<<PSZ_ * 2 / 256, 256, 0, stream>>>(
        lowb, highb, d1, d2, imin, gamma, fout, fnb);
    out_conv_tiled<<<800, 256, 0, stream>>>(fnb, wqo, out_b, oout);
}

// Round 10
// 210.039 us; speedup vs baseline: 1.1888x; 1.0455x over previous
//
#include <hip/hip_runtime.h>
#include <cmath>

#define N_   8
#define C_   64
#define H_   160
#define W_   160
#define HW_  25600
#define HH_  80
#define WH_  80
#define FSZ_ (N_ * C_ * HW_)   // 13,107,200
#define PSZ_ (N_ * HW_)        // 204,800

typedef unsigned short ushort8v __attribute__((ext_vector_type(8)));
typedef short          bf16x8  __attribute__((ext_vector_type(8)));
typedef float          f32x4   __attribute__((ext_vector_type(4)));

__device__ __forceinline__ float bf2f(unsigned short u) {
    return __uint_as_float(((unsigned)u) << 16);
}
__device__ __forceinline__ unsigned short f2bf(float f) {
    unsigned u = __float_as_uint(f);
    u += 0x7FFF + ((u >> 16) & 1);          // RNE
    return (unsigned short)(u >> 16);
}

// grid-sample setup: 4 tap indices + weights (align_corners=False, zeros pad)
__device__ __forceinline__ void gs_setup(float bgx, float bgy, float dx, float dy,
                                         int* idx, float* wgt)
{
    float px = ((bgx + dx * (1.f / 160.f)) + 1.f) * 80.f - 0.5f;
    float py = ((bgy + dy * (1.f / 160.f)) + 1.f) * 80.f - 0.5f;
    float x0f = floorf(px), y0f = floorf(py);
    float wx1 = px - x0f, wy1 = py - y0f, wx0 = 1.f - wx1, wy0 = 1.f - wy1;
    int x0 = (int)x0f, y0 = (int)y0f;
    float mx0 = ((unsigned)x0       < (unsigned)W_) ? 1.f : 0.f;
    float mx1 = ((unsigned)(x0 + 1) < (unsigned)W_) ? 1.f : 0.f;
    float my0 = ((unsigned)y0       < (unsigned)H_) ? 1.f : 0.f;
    float my1 = ((unsigned)(y0 + 1) < (unsigned)H_) ? 1.f : 0.f;
    int x0c = min(max(x0, 0), W_ - 1), x1c = min(max(x0 + 1, 0), W_ - 1);
    int y0c = min(max(y0, 0), H_ - 1), y1c = min(max(y0 + 1, 0), H_ - 1);
    idx[0] = y0c * W_ + x0c; wgt[0] = wy0 * wx0 * my0 * mx0;
    idx[1] = y0c * W_ + x1c; wgt[1] = wy0 * wx1 * my0 * mx1;
    idx[2] = y1c * W_ + x0c; wgt[2] = wy1 * wx0 * my1 * mx0;
    idx[3] = y1c * W_ + x1c; wgt[3] = wy1 * wx1 * my1 * mx1;
}

// -------- K0: weight prep --------
__global__ __launch_bounds__(256) void reorder_w_kernel(
    const float* __restrict__ w1a, const float* __restrict__ w1b,
    const float* __restrict__ s1, const float* __restrict__ b1,
    const float* __restrict__ m1, const float* __restrict__ v1,
    const float* __restrict__ s2, const float* __restrict__ b2,
    const float* __restrict__ m2, const float* __restrict__ v2,
    const float* __restrict__ w2a, const float* __restrict__ w2b,
    const float* __restrict__ ow,
    unsigned short* __restrict__ wqb, float* __restrict__ beta,
    unsigned short* __restrict__ wA, float* __restrict__ wqo)
{
    int tid = threadIdx.x;
    for (int i = tid; i < 16384; i += 256) {
        int j    = i & 7;
        int quad = (i >> 3) & 3;
        int co   = (i >> 5) & 127;
        int kb   = i >> 12;
        int k    = kb * 32 + quad * 8 + j;
        float wt, inv;
        if (co < 64) {
            wt  = w1a[co * 128 + k];
            inv = s1[co] * rsqrtf(v1[co] + 1e-5f);
        } else {
            wt  = w1b[(co - 64) * 128 + k];
            inv = s2[co - 64] * rsqrtf(v2[co - 64] + 1e-5f);
        }
        wqb[i] = f2bf(wt * inv);
    }
    for (int co = tid; co < 128; co += 256) {
        float inv, be;
        if (co < 64) {
            inv = s1[co] * rsqrtf(v1[co] + 1e-5f);
            be  = b1[co] - m1[co] * inv;
        } else {
            inv = s2[co - 64] * rsqrtf(v2[co - 64] + 1e-5f);
            be  = b2[co - 64] - m2[co - 64] * inv;
        }
        beta[co] = be;
    }
    for (int i = tid; i < 18432; i += 256) {
        int j    = i & 7;
        int lane = (i >> 3) & 63;
        int s    = (i >> 9) & 1;
        int t2   = i >> 10;
        int tap  = t2 % 9;
        int br   = t2 / 9;
        int row  = lane & 15;
        int ci   = s * 32 + (lane >> 4) * 8 + j;
        const float* src = br ? w2b : w2a;
        float v = (row < 2) ? src[row * 576 + ci * 9 + tap] : 0.f;
        wA[i] = f2bf(v);
    }
    for (int i = tid; i < 576; i += 256) {
        int tap = i / 64, ci = i % 64;
        wqo[i] = ow[ci * 9 + tap];
    }
}

// -------- K1: NCHW fp32 -> NHWC bf16 transpose (64 ch) --------
__global__ __launch_bounds__(256) void nchw_to_nhwc_bf16(
    const float* __restrict__ in, unsigned short* __restrict__ out, int hw)
{
    int p = blockIdx.x * 256 + threadIdx.x;
    int n = p / hw, rem = p % hw;
    const float* base = in + (long)n * 64 * hw + rem;
    unsigned o32[32];
    #pragma unroll
    for (int c2 = 0; c2 < 32; ++c2) {
        float v0 = base[(long)(2 * c2) * hw];
        float v1 = base[(long)(2 * c2 + 1) * hw];
        o32[c2] = (unsigned)f2bf(v0) | ((unsigned)f2bf(v1) << 16);
    }
    uint4* dst = reinterpret_cast<uint4*>(out + (long)p * 64);
    #pragma unroll
    for (int q = 0; q < 8; ++q)
        dst[q] = make_uint4(o32[q * 4], o32[q * 4 + 1], o32[q * 4 + 2], o32[q * 4 + 3]);
}

// -------- K2: bilinear resize 80->160 (align_corners=True) in NHWC bf16 -----
__global__ __launch_bounds__(256) void resize_high_nhwc(
    const unsigned short* __restrict__ hsb, unsigned short* __restrict__ highb)
{
    int p = blockIdx.x * 256 + threadIdx.x;
    int n = p / HW_, rem = p % HW_;
    int y = rem / W_, x = rem % W_;
    float sx = (x * 79.0f) / 159.0f;
    float sy = (y * 79.0f) / 159.0f;
    int ix0 = (int)sx, iy0 = (int)sy;
    float fx = sx - (float)ix0, fy = sy - (float)iy0;
    int ix1 = min(ix0 + 1, WH_ - 1), iy1 = min(iy0 + 1, HH_ - 1);
    long b = (long)n * (HH_ * WH_);
    const ushort8v* r00 = (const ushort8v*)(hsb + (b + iy0 * WH_ + ix0) * 64);
    const ushort8v* r01 = (const ushort8v*)(hsb + (b + iy0 * WH_ + ix1) * 64);
    const ushort8v* r10 = (const ushort8v*)(hsb + (b + iy1 * WH_ + ix0) * 64);
    const ushort8v* r11 = (const ushort8v*)(hsb + (b + iy1 * WH_ + ix1) * 64);
    float w00 = (1.f - fx) * (1.f - fy), w01 = fx * (1.f - fy);
    float w10 = (1.f - fx) * fy,         w11 = fx * fy;

    float acc[64];
    #pragma unroll
    for (int c = 0; c < 64; ++c) acc[c] = 0.f;
    #pragma unroll
    for (int q = 0; q < 8; ++q) {
        ushort8v v0 = r00[q], v1 = r01[q], v2 = r10[q], v3 = r11[q];
        #pragma unroll
        for (int j = 0; j < 8; ++j) {
            acc[q * 8 + j] = bf2f(v0[j]) * w00 + bf2f(v1[j]) * w01
                           + bf2f(v2[j]) * w10 + bf2f(v3[j]) * w11;
        }
    }
    unsigned o32[32];
    #pragma unroll
    for (int c2 = 0; c2 < 32; ++c2)
        o32[c2] = (unsigned)f2bf(acc[2 * c2]) | ((unsigned)f2bf(acc[2 * c2 + 1]) << 16);
    uint4* dst = reinterpret_cast<uint4*>(highb + (long)p * 64);
    #pragma unroll
    for (int q = 0; q < 8; ++q)
        dst[q] = make_uint4(o32[q * 4], o32[q * 4 + 1], o32[q * 4 + 2], o32[q * 4 + 3]);
}

// -------- K3: FUSED conv1x1(MFMA)+BN -> LDS -> conv3x3(MFMA) -> d1,d2 --------
// Tile 8x16 output, halo 10x18 = 180 px. 512 threads (8 waves) for occupancy.
__global__ __launch_bounds__(512) void fused13_kernel(
    const unsigned short* __restrict__ lowb, const unsigned short* __restrict__ highb,
    const unsigned short* __restrict__ wqb, const float* __restrict__ beta,
    const unsigned short* __restrict__ wA, float* __restrict__ d1,
    float* __restrict__ d2)
{
    __shared__ unsigned char lds[2 * 180 * 128];   // 46,080 B
    int b  = blockIdx.x;                  // 1600
    int n  = b / 200;
    int t  = b % 200;
    int ty = t / 10, tx = t % 10;         // 20 x 10 tiles of 8x16
    int y0 = ty * 8, x0 = tx * 16;
    int tid  = threadIdx.x;
    int lane = tid & 63;
    int wv   = tid >> 6;                  // 0..7
    int r16  = lane & 15;
    int quad = lane >> 4;
    long nb = (long)n * HW_;

    // ---- phase 1: 12 px-groups of 16 (180 valid) over 8 waves ----
    for (int g = wv; g < 12; g += 8) {
        int hp0 = g * 16 + r16;
        int hp  = min(hp0, 179);
        int py = hp / 18, px = hp - py * 18;
        int yy = y0 + py - 1, xx = x0 + px - 1;
        float vm = (((unsigned)yy < (unsigned)H_) && ((unsigned)xx < (unsigned)W_))
                 ? 1.f : 0.f;                       // conv zero-padding
        int gyc = min(max(yy, 0), H_ - 1);
        int gxc = min(max(xx, 0), W_ - 1);
        long prow = nb + gyc * W_ + gxc;

        const bf16x8* lr = (const bf16x8*)(lowb  + prow * 64);
        const bf16x8* hr = (const bf16x8*)(highb + prow * 64);
        bf16x8 afrag[4];
        afrag[0] = lr[quad];
        afrag[1] = lr[4 + quad];
        afrag[2] = hr[quad];
        afrag[3] = hr[4 + quad];

        f32x4 acc[8];
        #pragma unroll
        for (int ct = 0; ct < 8; ++ct) acc[ct] = (f32x4){0.f, 0.f, 0.f, 0.f};
        #pragma unroll
        for (int kb = 0; kb < 4; ++kb) {
            #pragma unroll
            for (int ct = 0; ct < 8; ++ct) {
                int co = ct * 16 + r16;
                bf16x8 bfr = *reinterpret_cast<const bf16x8*>(
                    wqb + (((kb * 128 + co) * 4 + quad) << 3));
                // swapped: weights as A (row=co), pixels as B (col=pixel)
                acc[ct] = __builtin_amdgcn_mfma_f32_16x16x32_bf16(
                    bfr, afrag[kb], acc[ct], 0, 0, 0);
            }
        }
        if (hp0 < 180) {
            #pragma unroll
            for (int ct = 0; ct < 8; ++ct) {
                int cob = ct * 16 + quad * 4;          // global co of reg 0
                float4 bet = *reinterpret_cast<const float4*>(beta + cob);
                unsigned lo = (unsigned)f2bf((acc[ct][0] + bet.x) * vm)
                            | ((unsigned)f2bf((acc[ct][1] + bet.y) * vm) << 16);
                unsigned hi = (unsigned)f2bf((acc[ct][2] + bet.z) * vm)
                            | ((unsigned)f2bf((acc[ct][3] + bet.w) * vm) << 16);
                int brof = (ct < 4) ? 0 : 23040;
                int cc2  = ((ct & 3) * 16 + quad * 4) * 2;   // byte off in row
                int byte = brof + ((hp0 * 128 + cc2) ^ ((hp0 & 7) << 4));
                *reinterpret_cast<uint2*>(lds + byte) = make_uint2(lo, hi);
            }
        }
    }
    __syncthreads();

    // ---- phase 2: conv3x3 via MFMA; wave wv owns output row wv ----
    f32x4 a1 = (f32x4){0.f, 0.f, 0.f, 0.f};
    f32x4 a2 = (f32x4){0.f, 0.f, 0.f, 0.f};

    #pragma unroll
    for (int tap = 0; tap < 9; ++tap) {
        int ky = tap / 3, kx = tap % 3;
        bf16x8 A10 = *reinterpret_cast<const bf16x8*>(
            wA + (((0 * 9 + tap) * 2 + 0) << 9) + lane * 8);
        bf16x8 A11 = *reinterpret_cast<const bf16x8*>(
            wA + (((0 * 9 + tap) * 2 + 1) << 9) + lane * 8);
        bf16x8 A20 = *reinterpret_cast<const bf16x8*>(
            wA + (((1 * 9 + tap) * 2 + 0) << 9) + lane * 8);
        bf16x8 A21 = *reinterpret_cast<const bf16x8*>(
            wA + (((1 * 9 + tap) * 2 + 1) << 9) + lane * 8);
        int tp = (wv + ky) * 18 + r16 + kx;
        int sw = (tp & 7) << 4;
        bf16x8 B10 = *reinterpret_cast<const bf16x8*>(
            lds + ((tp * 128 + quad * 16) ^ sw));
        bf16x8 B11 = *reinterpret_cast<const bf16x8*>(
            lds + ((tp * 128 + 64 + quad * 16) ^ sw));
        bf16x8 B20 = *reinterpret_cast<const bf16x8*>(
            lds + 23040 + ((tp * 128 + quad * 16) ^ sw));
        bf16x8 B21 = *reinterpret_cast<const bf16x8*>(
            lds + 23040 + ((tp * 128 + 64 + quad * 16) ^ sw));
        a1 = __builtin_amdgcn_mfma_f32_16x16x32_bf16(A10, B10, a1, 0, 0, 0);
        a1 = __builtin_amdgcn_mfma_f32_16x16x32_bf16(A11, B11, a1, 0, 0, 0);
        a2 = __builtin_amdgcn_mfma_f32_16x16x32_bf16(A20, B20, a2, 0, 0, 0);
        a2 = __builtin_amdgcn_mfma_f32_16x16x32_bf16(A21, B21, a2, 0, 0, 0);
    }
    if (quad == 0) {
        long p = nb + (y0 + wv) * W_ + x0 + r16;
        *reinterpret_cast<float2*>(d1 + p * 2) = make_float2(a1[0], a1[1]);
        *reinterpret_cast<float2*>(d2 + p * 2) = make_float2(a2[0], a2[1]);
    }
}

// -------- K4: warp+combine, channel-split (2 thr/px), imap inline --------
__global__ __launch_bounds__(256) void warp_combine_cs(
    const unsigned short* __restrict__ lowb, const unsigned short* __restrict__ highb,
    const float* __restrict__ d1, const float* __restrict__ d2,
    const float* __restrict__ imin, const float* __restrict__ gamma,
    float* __restrict__ f, unsigned short* __restrict__ fnb)
{
    int u = blockIdx.x * 256 + threadIdx.x;   // over 2*PSZ_
    int p = u >> 1, half = u & 1;
    int n = p / HW_, rem = p % HW_;
    int y = rem / W_, x = rem % W_;
    long nb = (long)n * HW_;

    float bgx = -1.f + x * (2.f / 159.f);
    float bgy = -1.f + y * (2.f / 159.f);

    float2 dv1 = *reinterpret_cast<const float2*>(d1 + (long)p * 2);
    float2 dv2 = *reinterpret_cast<const float2*>(d2 + (long)p * 2);

    int idx1[4], idx2[4];
    float wgt1[4], wgt2[4];
    gs_setup(bgx, bgy, dv1.x, dv1.y, idx1, wgt1);
    gs_setup(bgx, bgy, dv2.x, dv2.y, idx2, wgt2);

    // imap inline: bilinear(in_map, align_corners=True) + sigmoid
    float s;
    {
        float sx = (x * 79.0f) / 159.0f;
        float sy = (y * 79.0f) / 159.0f;
        int ix0 = (int)sx, iy0 = (int)sy;
        float fx = sx - (float)ix0, fy = sy - (float)iy0;
        int ix1 = min(ix0 + 1, WH_ - 1), iy1 = min(iy0 + 1, HH_ - 1);
        const float* ip = imin + n * (HH_ * WH_);
        float v00 = ip[iy0 * WH_ + ix0], v01 = ip[iy0 * WH_ + ix1];
        float v10 = ip[iy1 * WH_ + ix0], v11 = ip[iy1 * WH_ + ix1];
        float v = (v00 * (1.f - fx) + v01 * fx) * (1.f - fy)
                + (v10 * (1.f - fx) + v11 * fx) * fy;
        s = 1.f + gamma[0] * (1.f / (1.f + expf(-v)));
    }

    float acc[32];
    #pragma unroll
    for (int c = 0; c < 32; ++c) acc[c] = 0.f;

    #pragma unroll
    for (int j = 0; j < 4; ++j) {
        const ushort8v* row = (const ushort8v*)(highb + (nb + idx1[j]) * 64 + half * 32);
        float w = wgt1[j];
        #pragma unroll
        for (int q = 0; q < 4; ++q) {
            ushort8v v = row[q];
            #pragma unroll
            for (int k = 0; k < 8; ++k)
                acc[q * 8 + k] = fmaf(bf2f(v[k]), w, acc[q * 8 + k]);
        }
    }
    #pragma unroll
    for (int j = 0; j < 4; ++j) {
        const ushort8v* row = (const ushort8v*)(lowb + (nb + idx2[j]) * 64 + half * 32);
        float w = wgt2[j];
        #pragma unroll
        for (int q = 0; q < 4; ++q) {
            ushort8v v = row[q];
            #pragma unroll
            for (int k = 0; k < 8; ++k)
                acc[q * 8 + k] = fmaf(bf2f(v[k]), w, acc[q * 8 + k]);
        }
    }

    float* fp = f + nb * 64 + (long)(half * 32) * HW_ + rem;
    unsigned o32[16];
    #pragma unroll
    for (int c2 = 0; c2 < 16; ++c2) {
        float f0 = acc[2 * c2]     * s;
        float f1 = acc[2 * c2 + 1] * s;
        fp[(long)(2 * c2) * HW_]     = f0;
        fp[(long)(2 * c2 + 1) * HW_] = f1;
        o32[c2] = (unsigned)f2bf(f0) | ((unsigned)f2bf(f1) << 16);
    }
    uint4* dst = reinterpret_cast<uint4*>(fnb + (long)p * 64 + half * 32);
    #pragma unroll
    for (int q = 0; q < 4; ++q)
        dst[q] = make_uint4(o32[q * 4], o32[q * 4 + 1], o32[q * 4 + 2], o32[q * 4 + 3]);
}

// -------- K5: conv3x3 pad=1, bf16 NHWC 64->1 + bias, LDS-tiled --------
__global__ __launch_bounds__(256) void out_conv_tiled(
    const unsigned short* __restrict__ fnb, const float* __restrict__ wqo,
    const float* __restrict__ ob, float* __restrict__ o)
{
    __shared__ unsigned char lds[324 * 128];
    int b  = blockIdx.x;                   // 0..799
    int n  = b / 100;
    int t  = b % 100;
    int ty = t / 10, tx = t % 10;
    int y0 = ty * 16 - 1, x0 = tx * 16 - 1;
    int tid = threadIdx.x;

    for (int i = tid; i < 324 * 8; i += 256) {
        int pix = i >> 3, qq = i & 7;
        int py = pix / 18, px = pix % 18;
        int yy = min(max(y0 + py, 0), H_ - 1);
        int xx = min(max(x0 + px, 0), W_ - 1);
        ushort8v v = *reinterpret_cast<const ushort8v*>(
            fnb + ((long)(n * HW_ + yy * W_ + xx)) * 64 + qq * 8);
        *reinterpret_cast<ushort8v*>(
            lds + ((pix * 128 + qq * 16) ^ ((pix & 7) << 4))) = v;
    }
    __syncthreads();

    int oy = tid >> 4, ox = tid & 15;
    int gy = ty * 16 + oy, gx = tx * 16 + ox;

    float acc = 0.f;
    #pragma unroll
    for (int ky = 0; ky < 3; ++ky) {
        int yy = gy + ky - 1;
        float ym = ((unsigned)yy < (unsigned)H_) ? 1.f : 0.f;
        #pragma unroll
        for (int kx = 0; kx < 3; ++kx) {
            int xx = gx + kx - 1;
            float m = (((unsigned)xx < (unsigned)W_) ? 1.f : 0.f) * ym;
            int pix = (oy + ky) * 18 + (ox + kx);
            const float* wp = wqo + (ky * 3 + kx) * 64;
            float part = 0.f;
            #pragma unroll
            for (int qq = 0; qq < 8; ++qq) {
                ushort8v v = *reinterpret_cast<const ushort8v*>(
                    lds + ((pix * 128 + qq * 16) ^ ((pix & 7) << 4)));
                #pragma unroll
                for (int k = 0; k < 8; ++k)
                    part = fmaf(bf2f(v[k]), wp[qq * 8 + k], part);
            }
            acc = fmaf(m, part, acc);
        }
    }
    o[n * HW_ + gy * W_ + gx] = acc + ob[0];
}

extern "C" void kernel_launch(void* const* d_in, const int* in_sizes, int n_in,
                              void* d_out, int out_size, void* d_ws, size_t ws_size,
                              hipStream_t stream) {
    const float* low    = (const float*)d_in[0];
    const float* hsin   = (const float*)d_in[1];
    const float* imin   = (const float*)d_in[2];
    const float* dg1_w1 = (const float*)d_in[3];
    const float* dg1_s  = (const float*)d_in[4];
    const float* dg1_b  = (const float*)d_in[5];
    const float* dg1_m  = (const float*)d_in[6];
    const float* dg1_v  = (const float*)d_in[7];
    const float* dg1_w2 = (const float*)d_in[8];
    const float* dg2_w1 = (const float*)d_in[9];
    const float* dg2_s  = (const float*)d_in[10];
    const float* dg2_b  = (const float*)d_in[11];
    const float* dg2_m  = (const float*)d_in[12];
    const float* dg2_v  = (const float*)d_in[13];
    const float* dg2_w2 = (const float*)d_in[14];
    const float* gamma  = (const float*)d_in[15];
    const float* out_w  = (const float*)d_in[16];
    const float* out_b  = (const float*)d_in[17];

    float* ws   = (float*)d_ws;
    float* d1   = ws;                           // 2*PSZ_
    float* d2   = d1 + 2 * PSZ_;                // 2*PSZ_
    float* wqo  = d2 + 2 * PSZ_;                // 576
    float* beta = wqo + 576;                    // 128
    unsigned short* wqb   = (unsigned short*)(beta + 128);  // 16384
    unsigned short* wA    = wqb + 16384;        // 18432
    unsigned short* lowb  = wA + 18432;         // FSZ_ bf16 NHWC
    unsigned short* highb = lowb + FSZ_;        // FSZ_ bf16 NHWC
    unsigned short* fnb   = highb + FSZ_;       // FSZ_ bf16 NHWC
    unsigned short* hsb   = fnb;                // alias: hsb dead before fnb written

    float* fout = (float*)d_out;                // FSZ_ (output 0, NCHW fp32)
    float* oout = fout + FSZ_;                  // PSZ_ (output 1)

    reorder_w_kernel<<<1, 256, 0, stream>>>(
        dg1_w1, dg2_w1, dg1_s, dg1_b, dg1_m, dg1_v,
        dg2_s, dg2_b, dg2_m, dg2_v, dg1_w2, dg2_w2, out_w,
        wqb, beta, wA, wqo);
    nchw_to_nhwc_bf16<<<PSZ_ / 256, 256, 0, stream>>>(low, lowb, HW_);
    nchw_to_nhwc_bf16<<<(N_ * HH_ * WH_) / 256, 256, 0, stream>>>(hsin, hsb, HH_ * WH_);
    resize_high_nhwc<<<PSZ_ / 256, 256, 0, stream>>>(hsb, highb);
    fused13_kernel<<<1600, 512, 0, stream>>>(
        lowb, highb, wqb, beta, wA, d1, d2);
    warp_combine_cs<<<PSZ_ * 2 / 256, 256, 0, stream>>>(
        lowb, highb, d1, d2, imin, gamma, fout, fnb);
    out_conv_tiled<<<800, 256, 0, stream>>>(fnb, wqo, out_b, oout);
}